// Round 10
// baseline (268.005 us; speedup 1.0000x reference)
//
#include <hip/hip_runtime.h>
#include <cmath>
#include <cstddef>

#define BB 8
#define LL 2048
#define EE 512
#define HW 4096

typedef __attribute__((ext_vector_type(8))) short short8;
typedef __attribute__((ext_vector_type(4))) short short4v;
typedef __attribute__((ext_vector_type(4))) float f32x4;

// XOR-swizzled LDS index (bf16 elements). ldk = row length in bf16 elems.
__device__ __forceinline__ int swz(int row, int k, int ldk) {
    int g = (k >> 3) ^ (row & ((ldk >> 3) - 1));
    return row * ldk + (g << 3) + (k & 7);
}
__device__ __forceinline__ unsigned short f2bf(float f) {   // RNE f32->bf16
    unsigned u = __builtin_bit_cast(unsigned, f);
    return (unsigned short)((u + 0x7FFFu + ((u >> 16) & 1u)) >> 16);
}
__device__ __forceinline__ float bf2f(short s) {
    return __builtin_bit_cast(float, (unsigned)((unsigned short)s) << 16);
}
__device__ __forceinline__ short4v cvt4(float4 v) {
    short4v r;
    r[0] = (short)f2bf(v.x); r[1] = (short)f2bf(v.y);
    r[2] = (short)f2bf(v.z); r[3] = (short)f2bf(v.w);
    return r;
}
#define MFMA16(acc, a, b) acc = __builtin_amdgcn_mfma_f32_16x16x32_bf16(a, b, acc, 0, 0, 0)

// ---------------- K1: fused {weight reorder | gaussians | proj} ------------------
// blocks 0..287: reorder slice; blocks 0..255 also gauss; blocks 288..543: proj.
__global__ __launch_bounds__(256) void k_gauss_proj(const float* __restrict__ pos,
        const float* __restrict__ lsig,
        short* __restrict__ gyiT, short* __restrict__ gxiT,
        short* __restrict__ gyoT, short* __restrict__ gxo,
        const float* __restrict__ w1, const float* __restrict__ w2,
        short* __restrict__ w1b, short* __restrict__ w2b,
        const float* __restrict__ tokens, const float* __restrict__ wtf,
        short* __restrict__ projT) {
    __shared__ float red[4][4][64];
    __shared__ float tile[64 * 65];
    __shared__ __align__(16) short At[4096], Bt[4096];
    int t = threadIdx.x;
    int bx = blockIdx.x;

    if (bx >= 288) {   // ---------- proj path ----------
        int blk = bx - 288;
        int lane = t & 63, wid = t >> 6;
        int b = blk >> 5;
        int l0b = (blk & 31) * 64;
        size_t tokbase = ((size_t)b * LL + l0b) * EE;
        f32x4 z = {0.f, 0.f, 0.f, 0.f};
        f32x4 acc[4] = {z, z, z, z};
        float4 pa[4], pb[4];
        #pragma unroll
        for (int j = 0; j < 4; j++) {
            int idx = t + 256 * j;
            int row = idx >> 4, kq = (idx & 15) << 2;
            pa[j] = *(const float4*)&wtf[(size_t)row * EE + kq];
            pb[j] = *(const float4*)&tokens[tokbase + (size_t)row * EE + kq];
        }
        for (int c = 0; c < 8; c++) {
            __syncthreads();
            #pragma unroll
            for (int j = 0; j < 4; j++) {
                int idx = t + 256 * j;
                int row = idx >> 4, kq = (idx & 15) << 2;
                *(short4v*)&At[swz(row, kq, 64)] = cvt4(pa[j]);
                *(short4v*)&Bt[swz(row, kq, 64)] = cvt4(pb[j]);
            }
            __syncthreads();
            if (c < 7) {
                int e0 = (c + 1) * 64;
                #pragma unroll
                for (int j = 0; j < 4; j++) {
                    int idx = t + 256 * j;
                    int row = idx >> 4, kq = (idx & 15) << 2;
                    pa[j] = *(const float4*)&wtf[(size_t)row * EE + e0 + kq];
                    pb[j] = *(const float4*)&tokens[tokbase + (size_t)row * EE + e0 + kq];
                }
            }
            int mrow = wid * 16 + (lane & 15);
            #pragma unroll
            for (int ks = 0; ks < 2; ks++) {
                int k0 = ks * 32 + (lane >> 4) * 8;
                short8 a = *(short8*)&At[swz(mrow, k0, 64)];
                #pragma unroll
                for (int n = 0; n < 4; n++) {
                    short8 bb = *(short8*)&Bt[swz(n * 16 + (lane & 15), k0, 64)];
                    MFMA16(acc[n], a, bb);
                }
            }
        }
        #pragma unroll
        for (int n = 0; n < 4; n++)
            #pragma unroll
            for (int r = 0; r < 4; r++) {
                int d = wid * 16 + ((lane >> 4) << 2) + r;
                int l = l0b + n * 16 + (lane & 15);
                projT[((size_t)b * 64 + d) * LL + l] = (short)f2bf(acc[n][r]);
            }
        return;
    }

    {   // ---------- reorder slice (blocks 0..287) ----------
        int i = bx * 256 + t;
        if (i < 73728) {
            int c = i & 63, o = (i >> 6) & 127, tap = i >> 13;
            w1b[i] = (short)f2bf(w1[(size_t)o * 576 + c * 9 + tap]);
        }
        if (i < 8192) w2b[i] = (short)f2bf(w2[i]);
    }
    if (bx >= 256) return;
    // ---------- gauss path (blocks 0..255) ----------
    int ll = t & 63, q = t >> 6;
    int b = bx >> 5, lt = bx & 31;
    int bl = b * LL + lt * 64 + ll;
    float py = pos[(size_t)bl * 2 + 0];
    float px = pos[(size_t)bl * 2 + 1];
    float ls = lsig[0];
    float si = log1pf(expf(ls)) + 1e-6f;
    float so = si * 2.0f;
    float ai = 0.5f / (si * si), ao = 0.5f / (so * so);
    float vyi[16], vxi[16], vyo[16], vxo[16];
    float pyi = 0.f, pxi = 0.f, pyo = 0.f, pxo = 0.f;
    #pragma unroll
    for (int j = 0; j < 16; j++) {
        float g = (float)(q * 16 + j);
        float dy = g - py, dx = g - px;
        float dy2 = dy * dy, dx2 = dx * dx;
        vyi[j] = expf(-dy2 * ai); pyi += vyi[j];
        vxi[j] = expf(-dx2 * ai); pxi += vxi[j];
        vyo[j] = expf(-dy2 * ao); pyo += vyo[j];
        vxo[j] = expf(-dx2 * ao); pxo += vxo[j];
    }
    red[0][q][ll] = pyi; red[1][q][ll] = pxi;
    red[2][q][ll] = pyo; red[3][q][ll] = pxo;
    __syncthreads();
    float syi = red[0][0][ll] + red[0][1][ll] + red[0][2][ll] + red[0][3][ll];
    float sxi = red[1][0][ll] + red[1][1][ll] + red[1][2][ll] + red[1][3][ll];
    float syo = red[2][0][ll] + red[2][1][ll] + red[2][2][ll] + red[2][3][ll];
    float sxo = red[3][0][ll] + red[3][1][ll] + red[3][2][ll] + red[3][3][ll];
    float inv_i = 1.0f / (syi * sxi + 1e-6f);
    float inv_o = 1.0f / (syo * sxo + 1e-6f);
    size_t base = (size_t)b * 64 * LL + lt * 64 + ll;   // [b][*][l]
    #pragma unroll
    for (int j = 0; j < 16; j++) {
        size_t off = base + (size_t)(q * 16 + j) * LL;
        gyiT[off] = (short)f2bf(vyi[j] * inv_i);
        gxiT[off] = (short)f2bf(vxi[j]);
        gyoT[off] = (short)f2bf(vyo[j] * inv_o);
        tile[(q * 16 + j) * 65 + ll] = vxo[j];
    }
    __syncthreads();
    #pragma unroll
    for (int j = 0; j < 16; j++) {
        int i = t + 256 * j;
        int lo = i >> 6, wo = i & 63;
        gxo[((size_t)b * LL + lt * 64 + lo) * 64 + wo] = (short)f2bf(tile[wo * 65 + lo]);
    }
}

// ---------------- K3: scatter (kz=4 K-split, 128-l chunks) -> fz NHWC partials ----
__global__ __launch_bounds__(256, 3) void k_scatter(const short* __restrict__ projT,
        const short* __restrict__ gyiT, const short* __restrict__ gxiT,
        float* __restrict__ fz) {
    __shared__ __align__(16) char smem[49152];
    short* At = (short*)smem;               // proj [64 c][128 l] swz128
    short* B0 = At + 8192;                  // gx*gy0 [64 w][128 l]
    short* B1 = B0 + 8192;
    float* Cf = (float*)smem;               // epilogue overlay
    const size_t FP = (size_t)BB * 64 * HW; // 2M floats
    int t = threadIdx.x, lane = t & 63, wid = t >> 6;
    int hp = blockIdx.x, b = blockIdx.y, kz = blockIdx.z;
    int h0 = hp * 2;
    const short* pj  = projT + (size_t)b * 64 * LL + kz * 512;
    const short* gx  = gxiT + (size_t)b * 64 * LL + kz * 512;
    const short* gy0 = gyiT + ((size_t)b * 64 + h0) * LL + kz * 512;
    const short* gy1 = gy0 + LL;
    f32x4 z = {0.f, 0.f, 0.f, 0.f};
    f32x4 acc0[4] = {z, z, z, z}, acc1[4] = {z, z, z, z};
    int row_ = t >> 4, g_ = t & 15;
    short8 pA[4], pX[4], pY0v, pY1v;
    pY0v = *(const short8*)&gy0[g_ * 8];
    pY1v = *(const short8*)&gy1[g_ * 8];
    #pragma unroll
    for (int j = 0; j < 4; j++) {
        int row = row_ + 16 * j;
        pA[j] = *(const short8*)&pj[(size_t)row * LL + g_ * 8];
        pX[j] = *(const short8*)&gx[(size_t)row * LL + g_ * 8];
    }
    for (int c = 0; c < 4; c++) {
        __syncthreads();
        #pragma unroll
        for (int j = 0; j < 4; j++) {
            int row = row_ + 16 * j;
            short8 b0v, b1v;
            #pragma unroll
            for (int e = 0; e < 8; e++) {
                float gxv = bf2f(pX[j][e]);
                b0v[e] = (short)f2bf(gxv * bf2f(pY0v[e]));
                b1v[e] = (short)f2bf(gxv * bf2f(pY1v[e]));
            }
            *(short8*)&At[swz(row, g_ * 8, 128)] = pA[j];
            *(short8*)&B0[swz(row, g_ * 8, 128)] = b0v;
            *(short8*)&B1[swz(row, g_ * 8, 128)] = b1v;
        }
        __syncthreads();
        if (c < 3) {
            int off = (c + 1) * 128;
            pY0v = *(const short8*)&gy0[off + g_ * 8];
            pY1v = *(const short8*)&gy1[off + g_ * 8];
            #pragma unroll
            for (int j = 0; j < 4; j++) {
                int row = row_ + 16 * j;
                pA[j] = *(const short8*)&pj[(size_t)row * LL + off + g_ * 8];
                pX[j] = *(const short8*)&gx[(size_t)row * LL + off + g_ * 8];
            }
        }
        int mrow = wid * 16 + (lane & 15);
        #pragma unroll
        for (int ks = 0; ks < 4; ks++) {
            int k0 = ks * 32 + (lane >> 4) * 8;
            short8 a = *(short8*)&At[swz(mrow, k0, 128)];
            #pragma unroll
            for (int n = 0; n < 4; n++) {
                short8 b0f = *(short8*)&B0[swz(n * 16 + (lane & 15), k0, 128)];
                short8 b1f = *(short8*)&B1[swz(n * 16 + (lane & 15), k0, 128)];
                MFMA16(acc0[n], a, b0f);
                MFMA16(acc1[n], a, b1f);
            }
        }
    }
    float* dst = fz + (size_t)kz * FP;
    #pragma unroll
    for (int p = 0; p < 2; p++) {
        __syncthreads();
        #pragma unroll
        for (int n = 0; n < 4; n++)
            #pragma unroll
            for (int r = 0; r < 4; r++) {
                int w = n * 16 + (lane & 15);
                int cc = wid * 16 + ((lane >> 4) << 2) + r;
                Cf[w * 68 + cc] = (p == 0) ? acc0[n][r] : acc1[n][r];
            }
        __syncthreads();
        #pragma unroll
        for (int j = 0; j < 4; j++) {
            int i = t + 256 * j;
            int wo = i >> 4, cq = (i & 15) << 2;
            *(float4*)&dst[(((size_t)b * 64 + h0 + p) * 64 + wo) * 64 + cq] =
                *(float4*)&Cf[wo * 68 + cq];
        }
    }
}

// ---------------- K4: fused conv step (r5-verified body; nparts partial-sum) ------
__global__ __launch_bounds__(256, 3) void k_conv(const float* __restrict__ fin,
        int nparts, float* __restrict__ fout,
        const short* __restrict__ w1b, const float* __restrict__ b1,
        const short* __restrict__ w2b, const float* __restrict__ b2,
        short* __restrict__ fnchw, int final_step) {
    __shared__ __align__(16) char smem[45568];
    short* halo = (short*)smem;             // [100 px][64 c] swz64 (12800 B)
    short* w1t  = (short*)(smem + 12800);   // [128 o][64 c] swz64 (16384 B)
    short* ht   = (short*)(smem + 29184);   // [64 px][128 o] swz128 (16384 B)
    float* Cf   = (float*)smem;             // overlay for final epilogue (17408 B)
    const size_t FP = (size_t)BB * 64 * HW;
    int t = threadIdx.x, lane = t & 63, wid = t >> 6;
    int tile = blockIdx.x, b = blockIdx.y;
    int y0 = (tile >> 3) << 3, x0 = (tile & 7) << 3;
    const float* fb = fin + (size_t)b * 64 * HW;   // NHWC base

    // w2 fragments -> registers
    short8 w2f[4][4];
    #pragma unroll
    for (int n = 0; n < 4; n++)
        #pragma unroll
        for (int ks = 0; ks < 4; ks++)
            w2f[n][ks] = *(const short8*)&w2b[(size_t)(n * 16 + (lane & 15)) * 128
                                              + ks * 32 + (lane >> 4) * 8];
    // w1 tap0 prefetch
    short8 pf[4];
    #pragma unroll
    for (int j = 0; j < 4; j++) {
        int i = t + 256 * j; int o = i >> 3, g = i & 7;
        pf[j] = *(const short8*)&w1b[(size_t)o * 64 + g * 8];
    }
    // halo staging (sum nparts partials, f32 -> bf16, zero-padded)
    for (int i = t; i < 1600; i += 256) {
        int pix = i >> 4, cq = (i & 15) << 2;
        int pr = pix / 10, pc = pix - pr * 10;
        int gy = y0 + pr - 1, gx = x0 + pc - 1;
        float4 v = {0.f, 0.f, 0.f, 0.f};
        if ((unsigned)gy < 64u && (unsigned)gx < 64u) {
            size_t a = ((size_t)gy * 64 + gx) * 64 + cq;
            v = *(const float4*)&fb[a];
            for (int p = 1; p < nparts; p++) {
                float4 u = *(const float4*)&fb[(size_t)p * FP + a];
                v.x += u.x; v.y += u.y; v.z += u.z; v.w += u.w;
            }
        }
        *(short4v*)&halo[swz(pix, cq, 64)] = cvt4(v);
    }
    f32x4 accH[8];
    #pragma unroll
    for (int n = 0; n < 8; n++) {
        float bv = b1[n * 16 + (lane & 15)];
        f32x4 v = {bv, bv, bv, bv};
        accH[n] = v;
    }
    int mpix = wid * 16 + (lane & 15);
    int ppy = mpix >> 3, ppx = mpix & 7;

    #pragma unroll
    for (int tap = 0; tap < 9; tap++) {
        #pragma unroll
        for (int j = 0; j < 4; j++) {       // write w1t from prefetched regs
            int i = t + 256 * j; int o = i >> 3, g = i & 7;
            *(short8*)&w1t[swz(o, g * 8, 64)] = pf[j];
        }
        if (tap < 8) {                      // prefetch next tap
            #pragma unroll
            for (int j = 0; j < 4; j++) {
                int i = t + 256 * j; int o = i >> 3, g = i & 7;
                pf[j] = *(const short8*)&w1b[((size_t)(tap + 1) * 128 + o) * 64 + g * 8];
            }
        }
        __syncthreads();                    // w1t (and halo, tap0) ready
        int ky = tap / 3, kx = tap - ky * 3;
        int hpix = (ppy + ky) * 10 + (ppx + kx);
        #pragma unroll
        for (int ks = 0; ks < 2; ks++) {
            int k0 = ks * 32 + (lane >> 4) * 8;
            short8 a = *(short8*)&halo[swz(hpix, k0, 64)];
            #pragma unroll
            for (int n = 0; n < 8; n++) {
                short8 bb = *(short8*)&w1t[swz(n * 16 + (lane & 15), k0, 64)];
                MFMA16(accH[n], a, bb);
            }
        }
        __syncthreads();                    // w1t consumed
    }
    // relu -> ht (bf16)
    #pragma unroll
    for (int n = 0; n < 8; n++)
        #pragma unroll
        for (int r = 0; r < 4; r++) {
            int m = wid * 16 + ((lane >> 4) << 2) + r;
            int o = n * 16 + (lane & 15);
            ht[swz(m, o, 128)] = (short)f2bf(fmaxf(accH[n][r], 0.f));
        }
    __syncthreads();
    // conv2 (K=128) + bias, B from registers
    f32x4 acc2[4];
    #pragma unroll
    for (int n = 0; n < 4; n++) {
        float bv = b2[n * 16 + (lane & 15)];
        f32x4 v = {bv, bv, bv, bv};
        acc2[n] = v;
    }
    #pragma unroll
    for (int ks = 0; ks < 4; ks++) {
        int k0 = ks * 32 + (lane >> 4) * 8;
        short8 a = *(short8*)&ht[swz(mpix, k0, 128)];
        #pragma unroll
        for (int n = 0; n < 4; n++) MFMA16(acc2[n], a, w2f[n][ks]);
    }
    // residual (sum nparts) + store
    float* fo = fout + (size_t)b * 64 * HW;
    #pragma unroll
    for (int n = 0; n < 4; n++)
        #pragma unroll
        for (int r = 0; r < 4; r++) {
            int m = wid * 16 + ((lane >> 4) << 2) + r;
            int py = m >> 3, px = m & 7;
            int d = n * 16 + (lane & 15);
            size_t a = (((size_t)(y0 + py)) * 64 + x0 + px) * 64 + d;
            float fv = fb[a];
            for (int p = 1; p < nparts; p++) fv += fb[(size_t)p * FP + a];
            float val = acc2[n][r] + fv;
            if (!final_step) fo[a] = val;
            else Cf[d * 68 + m] = val;
        }
    if (final_step) {   // transpose to bf16 NCHW for gather
        __syncthreads();
        #pragma unroll
        for (int j = 0; j < 4; j++) {
            int i = t + 256 * j;
            int d = i >> 4, pq = (i & 15) << 2;
            int py = pq >> 3, px = pq & 7;
            float4 v = *(float4*)&Cf[d * 68 + pq];
            *(short4v*)&fnchw[(((size_t)b * 64 + d) * 64 + y0 + py) * 64 + x0 + px] =
                cvt4(v);
        }
    }
}

// ---------------- K5: gather (zz=8 z-split, 128-k chunks = 2 h) -> sampz ----------
__global__ __launch_bounds__(256, 4) void k_gather(const short* __restrict__ fnchw,
        const short* __restrict__ gyoT, const short* __restrict__ gxo,
        float* __restrict__ sampz) {
    __shared__ __align__(16) short At[8192], Bt[8192];   // [64][128] each
    int t = threadIdx.x, lane = t & 63, wid = t >> 6;
    int lt = blockIdx.x, b = blockIdx.y, zz = blockIdx.z;
    int l0 = lt * 64;
    f32x4 z4 = {0.f, 0.f, 0.f, 0.f};
    f32x4 acc[4] = {z4, z4, z4, z4};
    int row_ = t >> 4, g_ = t & 15;
    int hl_ = g_ >> 3, w8_ = (g_ & 7) * 8;   // granule -> (h_local, w-range)
    short8 pX[4], pB[4];
    float pY[4];
    #pragma unroll
    for (int j = 0; j < 4; j++) {            // chunk 0 prefetch; pX chunk-invariant
        int row = row_ + 16 * j;
        int h = zz * 8 + hl_;
        pX[j] = *(const short8*)&gxo[((size_t)b * LL + l0 + row) * 64 + w8_];
        pY[j] = bf2f(gyoT[((size_t)b * 64 + h) * LL + l0 + row]);
        pB[j] = *(const short8*)&fnchw[(((size_t)b * 64 + row) * 64 + h) * 64 + w8_];
    }
    for (int c = 0; c < 4; c++) {
        __syncthreads();
        #pragma unroll
        for (int j = 0; j < 4; j++) {
            int row = row_ + 16 * j;
            short8 a;
            #pragma unroll
            for (int e = 0; e < 8; e++)
                a[e] = (short)f2bf(bf2f(pX[j][e]) * pY[j]);
            *(short8*)&At[swz(row, g_ * 8, 128)] = a;
            *(short8*)&Bt[swz(row, g_ * 8, 128)] = pB[j];
        }
        __syncthreads();
        if (c < 3) {
            int h = zz * 8 + (c + 1) * 2 + hl_;
            #pragma unroll
            for (int j = 0; j < 4; j++) {
                int row = row_ + 16 * j;
                pY[j] = bf2f(gyoT[((size_t)b * 64 + h) * LL + l0 + row]);
                pB[j] = *(const short8*)&fnchw[(((size_t)b * 64 + row) * 64 + h) * 64 + w8_];
            }
        }
        int mrow = wid * 16 + (lane & 15);
        #pragma unroll
        for (int ks = 0; ks < 4; ks++) {
            int k0 = ks * 32 + (lane >> 4) * 8;
            short8 a = *(short8*)&At[swz(mrow, k0, 128)];
            #pragma unroll
            for (int n = 0; n < 4; n++) {
                short8 bb = *(short8*)&Bt[swz(n * 16 + (lane & 15), k0, 128)];
                MFMA16(acc[n], a, bb);
            }
        }
    }
    #pragma unroll
    for (int n = 0; n < 4; n++)
        #pragma unroll
        for (int r = 0; r < 4; r++) {
            int lr = wid * 16 + ((lane >> 4) << 2) + r;
            int cc = n * 16 + (lane & 15);
            sampz[(((size_t)zz * BB + b) * LL + l0 + lr) * 64 + cc] = acc[n][r];
        }
}

// ---------------- K6: out[bl][e] = sum_d (sum_z samp[z])[bl][d] * wff[e][d] -------
__global__ __launch_bounds__(256) void k_out(const float* __restrict__ samp,
        const float* __restrict__ wff, float* __restrict__ out) {
    __shared__ __align__(16) short At[4096], Bt[4096];
    const size_t SP = 1048576;
    int t = threadIdx.x, lane = t & 63, wid = t >> 6;
    int mt = blockIdx.x, e0 = blockIdx.y * 64;
    #pragma unroll
    for (int j = 0; j < 4; j++) {
        int idx = t + 256 * j;
        int row = idx >> 4, kq = (idx & 15) << 2;
        size_t off = ((size_t)mt * 64 + row) * 64 + kq;
        float4 vs = {0.f, 0.f, 0.f, 0.f};
        #pragma unroll
        for (int zp = 0; zp < 8; zp++) {
            float4 v = *(const float4*)&samp[off + (size_t)zp * SP];
            vs.x += v.x; vs.y += v.y; vs.z += v.z; vs.w += v.w;
        }
        *(short4v*)&At[swz(row, kq, 64)] = cvt4(vs);
        float4 wv = *(const float4*)&wff[(size_t)(e0 + row) * 64 + kq];
        *(short4v*)&Bt[swz(row, kq, 64)] = cvt4(wv);
    }
    __syncthreads();
    f32x4 z = {0.f, 0.f, 0.f, 0.f};
    f32x4 acc[4] = {z, z, z, z};
    int mrow = wid * 16 + (lane & 15);
    #pragma unroll
    for (int ks = 0; ks < 2; ks++) {
        int k0 = ks * 32 + (lane >> 4) * 8;
        short8 a = *(short8*)&At[swz(mrow, k0, 64)];
        #pragma unroll
        for (int n = 0; n < 4; n++) {
            short8 bb = *(short8*)&Bt[swz(n * 16 + (lane & 15), k0, 64)];
            MFMA16(acc[n], a, bb);
        }
    }
    #pragma unroll
    for (int n = 0; n < 4; n++)
        #pragma unroll
        for (int r = 0; r < 4; r++) {
            int lr = wid * 16 + ((lane >> 4) << 2) + r;
            int ec = e0 + n * 16 + (lane & 15);
            out[((size_t)mt * 64 + lr) * EE + ec] = acc[n][r];
        }
}

extern "C" void kernel_launch(void* const* d_in, const int* in_sizes, int n_in,
                              void* d_out, int out_size, void* d_ws, size_t ws_size,
                              hipStream_t stream) {
    const float* tokens = (const float*)d_in[0];
    const float* pos    = (const float*)d_in[1];
    const float* wtf    = (const float*)d_in[2];
    const float* wff    = (const float*)d_in[3];
    const float* w1     = (const float*)d_in[4];
    const float* b1     = (const float*)d_in[5];
    const float* w2     = (const float*)d_in[6];
    const float* b2     = (const float*)d_in[7];
    const float* lsig   = (const float*)d_in[8];
    float* out = (float*)d_out;

    const size_t M1 = 1048576;
    float* ws    = (float*)d_ws;
    short* sbase = (short*)d_ws;
    short* gyiT  = sbase;               // [0,1M) shorts
    short* gxiT  = sbase + 1 * M1;      // [1M,2M)
    short* gyoT  = sbase + 2 * M1;      // [2M,3M)
    short* gxo   = sbase + 3 * M1;      // [3M,4M)
    short* projT = sbase + 4 * M1;      // [4M,5M) shorts = floats [2M,2.5M)
    float* fz    = ws + 3 * M1;         // 4 x 2M floats [3M,11M) (scatter partials)
    float* fA    = ws + 11 * M1;        // 2M floats NHWC
    float* fB    = ws + 13 * M1;        // 2M floats NHWC
    short* fnchw = (short*)(ws + 15 * M1);  // 2M shorts (bf16 NCHW) [15M,16M)
    float* samp  = ws + 16 * M1;        // 8 x 1M floats [16M,24M) (gather partials)
    short* w1b   = (short*)(ws + 24 * M1);  // 73728 bf16
    short* w2b   = w1b + 73728;             // 8192 bf16

    hipLaunchKernelGGL(k_gauss_proj, dim3(544), dim3(256), 0, stream,
                       pos, lsig, gyiT, gxiT, gyoT, gxo, w1, w2, w1b, w2b,
                       tokens, wtf, projT);
    hipLaunchKernelGGL(k_scatter, dim3(32, 8, 4), dim3(256), 0, stream,
                       projT, gyiT, gxiT, fz);
    hipLaunchKernelGGL(k_conv, dim3(64, 8), dim3(256), 0, stream,
                       fz, 4, fB, w1b, b1, w2b, b2, fnchw, 0);
    hipLaunchKernelGGL(k_conv, dim3(64, 8), dim3(256), 0, stream,
                       fB, 1, fA, w1b, b1, w2b, b2, fnchw, 0);
    hipLaunchKernelGGL(k_conv, dim3(64, 8), dim3(256), 0, stream,
                       fA, 1, fB, w1b, b1, w2b, b2, fnchw, 0);
    hipLaunchKernelGGL(k_conv, dim3(64, 8), dim3(256), 0, stream,
                       fB, 1, fA, w1b, b1, w2b, b2, fnchw, 0);
    hipLaunchKernelGGL(k_conv, dim3(64, 8), dim3(256), 0, stream,
                       fA, 1, fB, w1b, b1, w2b, b2, fnchw, 1);
    hipLaunchKernelGGL(k_gather, dim3(32, 8, 8), dim3(256), 0, stream,
                       fnchw, gyoT, gxo, samp);
    hipLaunchKernelGGL(k_out, dim3(256, 8), dim3(256), 0, stream,
                       samp, wff, out);
}

// Round 11
// 237.880 us; speedup vs baseline: 1.1266x; 1.1266x over previous
//
#include <hip/hip_runtime.h>
#include <cmath>
#include <cstddef>

#define BB 8
#define LL 2048
#define EE 512
#define HW 4096

typedef __attribute__((ext_vector_type(8))) short short8;
typedef __attribute__((ext_vector_type(4))) short short4v;
typedef __attribute__((ext_vector_type(4))) float f32x4;

// XOR-swizzled LDS index (bf16 elements). ldk = row length in bf16 elems.
__device__ __forceinline__ int swz(int row, int k, int ldk) {
    int g = (k >> 3) ^ (row & ((ldk >> 3) - 1));
    return row * ldk + (g << 3) + (k & 7);
}
__device__ __forceinline__ unsigned short f2bf(float f) {   // RNE f32->bf16
    unsigned u = __builtin_bit_cast(unsigned, f);
    return (unsigned short)((u + 0x7FFFu + ((u >> 16) & 1u)) >> 16);
}
__device__ __forceinline__ float bf2f(short s) {
    return __builtin_bit_cast(float, (unsigned)((unsigned short)s) << 16);
}
__device__ __forceinline__ short4v cvt4(float4 v) {
    short4v r;
    r[0] = (short)f2bf(v.x); r[1] = (short)f2bf(v.y);
    r[2] = (short)f2bf(v.z); r[3] = (short)f2bf(v.w);
    return r;
}
#define MFMA16(acc, a, b) acc = __builtin_amdgcn_mfma_f32_16x16x32_bf16(a, b, acc, 0, 0, 0)

// ---------------- K1: fused {weight reorder | gaussians | proj} ------------------
// blocks 0..287: reorder slice; blocks 0..255 also gauss; blocks 288..543: proj.
__global__ __launch_bounds__(256) void k_gauss_proj(const float* __restrict__ pos,
        const float* __restrict__ lsig,
        short* __restrict__ gyiT, short* __restrict__ gxiT,
        short* __restrict__ gyoT, short* __restrict__ gxo,
        const float* __restrict__ w1, const float* __restrict__ w2,
        short* __restrict__ w1b, short* __restrict__ w2b,
        const float* __restrict__ tokens, const float* __restrict__ wtf,
        short* __restrict__ projT) {
    __shared__ float red[4][4][64];
    __shared__ float tile[64 * 65];
    __shared__ __align__(16) short At[4096], Bt[4096];
    int t = threadIdx.x;
    int bx = blockIdx.x;

    if (bx >= 288) {   // ---------- proj path ----------
        int blk = bx - 288;
        int lane = t & 63, wid = t >> 6;
        int b = blk >> 5;
        int l0b = (blk & 31) * 64;
        size_t tokbase = ((size_t)b * LL + l0b) * EE;
        f32x4 z = {0.f, 0.f, 0.f, 0.f};
        f32x4 acc[4] = {z, z, z, z};
        float4 pa[4], pb[4];
        #pragma unroll
        for (int j = 0; j < 4; j++) {
            int idx = t + 256 * j;
            int row = idx >> 4, kq = (idx & 15) << 2;
            pa[j] = *(const float4*)&wtf[(size_t)row * EE + kq];
            pb[j] = *(const float4*)&tokens[tokbase + (size_t)row * EE + kq];
        }
        for (int c = 0; c < 8; c++) {
            __syncthreads();
            #pragma unroll
            for (int j = 0; j < 4; j++) {
                int idx = t + 256 * j;
                int row = idx >> 4, kq = (idx & 15) << 2;
                *(short4v*)&At[swz(row, kq, 64)] = cvt4(pa[j]);
                *(short4v*)&Bt[swz(row, kq, 64)] = cvt4(pb[j]);
            }
            __syncthreads();
            if (c < 7) {
                int e0 = (c + 1) * 64;
                #pragma unroll
                for (int j = 0; j < 4; j++) {
                    int idx = t + 256 * j;
                    int row = idx >> 4, kq = (idx & 15) << 2;
                    pa[j] = *(const float4*)&wtf[(size_t)row * EE + e0 + kq];
                    pb[j] = *(const float4*)&tokens[tokbase + (size_t)row * EE + e0 + kq];
                }
            }
            int mrow = wid * 16 + (lane & 15);
            #pragma unroll
            for (int ks = 0; ks < 2; ks++) {
                int k0 = ks * 32 + (lane >> 4) * 8;
                short8 a = *(short8*)&At[swz(mrow, k0, 64)];
                #pragma unroll
                for (int n = 0; n < 4; n++) {
                    short8 bb = *(short8*)&Bt[swz(n * 16 + (lane & 15), k0, 64)];
                    MFMA16(acc[n], a, bb);
                }
            }
        }
        #pragma unroll
        for (int n = 0; n < 4; n++)
            #pragma unroll
            for (int r = 0; r < 4; r++) {
                int d = wid * 16 + ((lane >> 4) << 2) + r;
                int l = l0b + n * 16 + (lane & 15);
                projT[((size_t)b * 64 + d) * LL + l] = (short)f2bf(acc[n][r]);
            }
        return;
    }

    {   // ---------- reorder slice (blocks 0..287) ----------
        int i = bx * 256 + t;
        if (i < 73728) {
            int c = i & 63, o = (i >> 6) & 127, tap = i >> 13;
            w1b[i] = (short)f2bf(w1[(size_t)o * 576 + c * 9 + tap]);
        }
        if (i < 8192) w2b[i] = (short)f2bf(w2[i]);
    }
    if (bx >= 256) return;
    // ---------- gauss path (blocks 0..255) ----------
    int ll = t & 63, q = t >> 6;
    int b = bx >> 5, lt = bx & 31;
    int bl = b * LL + lt * 64 + ll;
    float py = pos[(size_t)bl * 2 + 0];
    float px = pos[(size_t)bl * 2 + 1];
    float ls = lsig[0];
    float si = log1pf(expf(ls)) + 1e-6f;
    float so = si * 2.0f;
    float ai = 0.5f / (si * si), ao = 0.5f / (so * so);
    float vyi[16], vxi[16], vyo[16], vxo[16];
    float pyi = 0.f, pxi = 0.f, pyo = 0.f, pxo = 0.f;
    #pragma unroll
    for (int j = 0; j < 16; j++) {
        float g = (float)(q * 16 + j);
        float dy = g - py, dx = g - px;
        float dy2 = dy * dy, dx2 = dx * dx;
        vyi[j] = expf(-dy2 * ai); pyi += vyi[j];
        vxi[j] = expf(-dx2 * ai); pxi += vxi[j];
        vyo[j] = expf(-dy2 * ao); pyo += vyo[j];
        vxo[j] = expf(-dx2 * ao); pxo += vxo[j];
    }
    red[0][q][ll] = pyi; red[1][q][ll] = pxi;
    red[2][q][ll] = pyo; red[3][q][ll] = pxo;
    __syncthreads();
    float syi = red[0][0][ll] + red[0][1][ll] + red[0][2][ll] + red[0][3][ll];
    float sxi = red[1][0][ll] + red[1][1][ll] + red[1][2][ll] + red[1][3][ll];
    float syo = red[2][0][ll] + red[2][1][ll] + red[2][2][ll] + red[2][3][ll];
    float sxo = red[3][0][ll] + red[3][1][ll] + red[3][2][ll] + red[3][3][ll];
    float inv_i = 1.0f / (syi * sxi + 1e-6f);
    float inv_o = 1.0f / (syo * sxo + 1e-6f);
    size_t base = (size_t)b * 64 * LL + lt * 64 + ll;   // [b][*][l]
    #pragma unroll
    for (int j = 0; j < 16; j++) {
        size_t off = base + (size_t)(q * 16 + j) * LL;
        gyiT[off] = (short)f2bf(vyi[j] * inv_i);
        gxiT[off] = (short)f2bf(vxi[j]);
        gyoT[off] = (short)f2bf(vyo[j] * inv_o);
        tile[(q * 16 + j) * 65 + ll] = vxo[j];
    }
    __syncthreads();
    #pragma unroll
    for (int j = 0; j < 16; j++) {
        int i = t + 256 * j;
        int lo = i >> 6, wo = i & 63;
        gxo[((size_t)b * LL + lt * 64 + lo) * 64 + wo] = (short)f2bf(tile[wo * 65 + lo]);
    }
}

// ---------------- K3: scatter (kz=2 K-split, 128-l chunks) -> fz NHWC partials ----
// grid (b, hp, kz): b in blockIdx.x so linear-ID%8 == b -> batch->XCD affinity.
__global__ __launch_bounds__(256, 3) void k_scatter(const short* __restrict__ projT,
        const short* __restrict__ gyiT, const short* __restrict__ gxiT,
        float* __restrict__ fz) {
    __shared__ __align__(16) char smem[49152];
    short* At = (short*)smem;               // proj [64 c][128 l] swz128
    short* B0 = At + 8192;                  // gx*gy0 [64 w][128 l]
    short* B1 = B0 + 8192;
    float* Cf = (float*)smem;               // epilogue overlay
    const size_t FP = (size_t)BB * 64 * HW; // 2M floats
    int t = threadIdx.x, lane = t & 63, wid = t >> 6;
    int b = blockIdx.x, hp = blockIdx.y, kz = blockIdx.z;
    int h0 = hp * 2;
    const short* pj  = projT + (size_t)b * 64 * LL + kz * 1024;
    const short* gx  = gxiT + (size_t)b * 64 * LL + kz * 1024;
    const short* gy0 = gyiT + ((size_t)b * 64 + h0) * LL + kz * 1024;
    const short* gy1 = gy0 + LL;
    f32x4 z = {0.f, 0.f, 0.f, 0.f};
    f32x4 acc0[4] = {z, z, z, z}, acc1[4] = {z, z, z, z};
    int row_ = t >> 4, g_ = t & 15;
    short8 pA[4], pX[4], pY0v, pY1v;
    pY0v = *(const short8*)&gy0[g_ * 8];
    pY1v = *(const short8*)&gy1[g_ * 8];
    #pragma unroll
    for (int j = 0; j < 4; j++) {
        int row = row_ + 16 * j;
        pA[j] = *(const short8*)&pj[(size_t)row * LL + g_ * 8];
        pX[j] = *(const short8*)&gx[(size_t)row * LL + g_ * 8];
    }
    for (int c = 0; c < 8; c++) {
        __syncthreads();
        #pragma unroll
        for (int j = 0; j < 4; j++) {
            int row = row_ + 16 * j;
            short8 b0v, b1v;
            #pragma unroll
            for (int e = 0; e < 8; e++) {
                float gxv = bf2f(pX[j][e]);
                b0v[e] = (short)f2bf(gxv * bf2f(pY0v[e]));
                b1v[e] = (short)f2bf(gxv * bf2f(pY1v[e]));
            }
            *(short8*)&At[swz(row, g_ * 8, 128)] = pA[j];
            *(short8*)&B0[swz(row, g_ * 8, 128)] = b0v;
            *(short8*)&B1[swz(row, g_ * 8, 128)] = b1v;
        }
        __syncthreads();
        if (c < 7) {
            int off = (c + 1) * 128;
            pY0v = *(const short8*)&gy0[off + g_ * 8];
            pY1v = *(const short8*)&gy1[off + g_ * 8];
            #pragma unroll
            for (int j = 0; j < 4; j++) {
                int row = row_ + 16 * j;
                pA[j] = *(const short8*)&pj[(size_t)row * LL + off + g_ * 8];
                pX[j] = *(const short8*)&gx[(size_t)row * LL + off + g_ * 8];
            }
        }
        int mrow = wid * 16 + (lane & 15);
        #pragma unroll
        for (int ks = 0; ks < 4; ks++) {
            int k0 = ks * 32 + (lane >> 4) * 8;
            short8 a = *(short8*)&At[swz(mrow, k0, 128)];
            #pragma unroll
            for (int n = 0; n < 4; n++) {
                short8 b0f = *(short8*)&B0[swz(n * 16 + (lane & 15), k0, 128)];
                short8 b1f = *(short8*)&B1[swz(n * 16 + (lane & 15), k0, 128)];
                MFMA16(acc0[n], a, b0f);
                MFMA16(acc1[n], a, b1f);
            }
        }
    }
    float* dst = fz + (size_t)kz * FP;
    #pragma unroll
    for (int p = 0; p < 2; p++) {
        __syncthreads();
        #pragma unroll
        for (int n = 0; n < 4; n++)
            #pragma unroll
            for (int r = 0; r < 4; r++) {
                int w = n * 16 + (lane & 15);
                int cc = wid * 16 + ((lane >> 4) << 2) + r;
                Cf[w * 68 + cc] = (p == 0) ? acc0[n][r] : acc1[n][r];
            }
        __syncthreads();
        #pragma unroll
        for (int j = 0; j < 4; j++) {
            int i = t + 256 * j;
            int wo = i >> 4, cq = (i & 15) << 2;
            *(float4*)&dst[(((size_t)b * 64 + h0 + p) * 64 + wo) * 64 + cq] =
                *(float4*)&Cf[wo * 68 + cq];
        }
    }
}

// ---------------- K4: fused conv step (r5-verified body; grid (b, tile)) ----------
__global__ __launch_bounds__(256, 3) void k_conv(const float* __restrict__ fin,
        int nparts, float* __restrict__ fout,
        const short* __restrict__ w1b, const float* __restrict__ b1,
        const short* __restrict__ w2b, const float* __restrict__ b2,
        short* __restrict__ fnchw, int final_step) {
    __shared__ __align__(16) char smem[45568];
    short* halo = (short*)smem;             // [100 px][64 c] swz64 (12800 B)
    short* w1t  = (short*)(smem + 12800);   // [128 o][64 c] swz64 (16384 B)
    short* ht   = (short*)(smem + 29184);   // [64 px][128 o] swz128 (16384 B)
    float* Cf   = (float*)smem;             // overlay for final epilogue (17408 B)
    const size_t FP = (size_t)BB * 64 * HW;
    int t = threadIdx.x, lane = t & 63, wid = t >> 6;
    int b = blockIdx.x, tile = blockIdx.y;  // b fastest -> XCD affinity
    int y0 = (tile >> 3) << 3, x0 = (tile & 7) << 3;
    const float* fb = fin + (size_t)b * 64 * HW;   // NHWC base

    // w2 fragments -> registers
    short8 w2f[4][4];
    #pragma unroll
    for (int n = 0; n < 4; n++)
        #pragma unroll
        for (int ks = 0; ks < 4; ks++)
            w2f[n][ks] = *(const short8*)&w2b[(size_t)(n * 16 + (lane & 15)) * 128
                                              + ks * 32 + (lane >> 4) * 8];
    // w1 tap0 prefetch
    short8 pf[4];
    #pragma unroll
    for (int j = 0; j < 4; j++) {
        int i = t + 256 * j; int o = i >> 3, g = i & 7;
        pf[j] = *(const short8*)&w1b[(size_t)o * 64 + g * 8];
    }
    // halo staging (sum nparts partials, f32 -> bf16, zero-padded)
    for (int i = t; i < 1600; i += 256) {
        int pix = i >> 4, cq = (i & 15) << 2;
        int pr = pix / 10, pc = pix - pr * 10;
        int gy = y0 + pr - 1, gx = x0 + pc - 1;
        float4 v = {0.f, 0.f, 0.f, 0.f};
        if ((unsigned)gy < 64u && (unsigned)gx < 64u) {
            size_t a = ((size_t)gy * 64 + gx) * 64 + cq;
            v = *(const float4*)&fb[a];
            for (int p = 1; p < nparts; p++) {
                float4 u = *(const float4*)&fb[(size_t)p * FP + a];
                v.x += u.x; v.y += u.y; v.z += u.z; v.w += u.w;
            }
        }
        *(short4v*)&halo[swz(pix, cq, 64)] = cvt4(v);
    }
    f32x4 accH[8];
    #pragma unroll
    for (int n = 0; n < 8; n++) {
        float bv = b1[n * 16 + (lane & 15)];
        f32x4 v = {bv, bv, bv, bv};
        accH[n] = v;
    }
    int mpix = wid * 16 + (lane & 15);
    int ppy = mpix >> 3, ppx = mpix & 7;

    #pragma unroll
    for (int tap = 0; tap < 9; tap++) {
        #pragma unroll
        for (int j = 0; j < 4; j++) {       // write w1t from prefetched regs
            int i = t + 256 * j; int o = i >> 3, g = i & 7;
            *(short8*)&w1t[swz(o, g * 8, 64)] = pf[j];
        }
        if (tap < 8) {                      // prefetch next tap
            #pragma unroll
            for (int j = 0; j < 4; j++) {
                int i = t + 256 * j; int o = i >> 3, g = i & 7;
                pf[j] = *(const short8*)&w1b[((size_t)(tap + 1) * 128 + o) * 64 + g * 8];
            }
        }
        __syncthreads();                    // w1t (and halo, tap0) ready
        int ky = tap / 3, kx = tap - ky * 3;
        int hpix = (ppy + ky) * 10 + (ppx + kx);
        #pragma unroll
        for (int ks = 0; ks < 2; ks++) {
            int k0 = ks * 32 + (lane >> 4) * 8;
            short8 a = *(short8*)&halo[swz(hpix, k0, 64)];
            #pragma unroll
            for (int n = 0; n < 8; n++) {
                short8 bb = *(short8*)&w1t[swz(n * 16 + (lane & 15), k0, 64)];
                MFMA16(accH[n], a, bb);
            }
        }
        __syncthreads();                    // w1t consumed
    }
    // relu -> ht (bf16)
    #pragma unroll
    for (int n = 0; n < 8; n++)
        #pragma unroll
        for (int r = 0; r < 4; r++) {
            int m = wid * 16 + ((lane >> 4) << 2) + r;
            int o = n * 16 + (lane & 15);
            ht[swz(m, o, 128)] = (short)f2bf(fmaxf(accH[n][r], 0.f));
        }
    __syncthreads();
    // conv2 (K=128) + bias, B from registers
    f32x4 acc2[4];
    #pragma unroll
    for (int n = 0; n < 4; n++) {
        float bv = b2[n * 16 + (lane & 15)];
        f32x4 v = {bv, bv, bv, bv};
        acc2[n] = v;
    }
    #pragma unroll
    for (int ks = 0; ks < 4; ks++) {
        int k0 = ks * 32 + (lane >> 4) * 8;
        short8 a = *(short8*)&ht[swz(mpix, k0, 128)];
        #pragma unroll
        for (int n = 0; n < 4; n++) MFMA16(acc2[n], a, w2f[n][ks]);
    }
    // residual (sum nparts) + store
    float* fo = fout + (size_t)b * 64 * HW;
    #pragma unroll
    for (int n = 0; n < 4; n++)
        #pragma unroll
        for (int r = 0; r < 4; r++) {
            int m = wid * 16 + ((lane >> 4) << 2) + r;
            int py = m >> 3, px = m & 7;
            int d = n * 16 + (lane & 15);
            size_t a = (((size_t)(y0 + py)) * 64 + x0 + px) * 64 + d;
            float fv = fb[a];
            for (int p = 1; p < nparts; p++) fv += fb[(size_t)p * FP + a];
            float val = acc2[n][r] + fv;
            if (!final_step) fo[a] = val;
            else Cf[d * 68 + m] = val;
        }
    if (final_step) {   // transpose to bf16 NCHW for gather
        __syncthreads();
        #pragma unroll
        for (int j = 0; j < 4; j++) {
            int i = t + 256 * j;
            int d = i >> 4, pq = (i & 15) << 2;
            int py = pq >> 3, px = pq & 7;
            float4 v = *(float4*)&Cf[d * 68 + pq];
            *(short4v*)&fnchw[(((size_t)b * 64 + d) * 64 + y0 + py) * 64 + x0 + px] =
                cvt4(v);
        }
    }
}

// ---------------- K5: gather (zz=4 z-split, 128-k chunks = 2 h) -> sampz ----------
__global__ __launch_bounds__(256, 4) void k_gather(const short* __restrict__ fnchw,
        const short* __restrict__ gyoT, const short* __restrict__ gxo,
        float* __restrict__ sampz) {
    __shared__ __align__(16) short At[8192], Bt[8192];   // [64][128] each
    int t = threadIdx.x, lane = t & 63, wid = t >> 6;
    int b = blockIdx.x, lt = blockIdx.y, zz = blockIdx.z;  // b fastest -> XCD affinity
    int l0 = lt * 64;
    f32x4 z4 = {0.f, 0.f, 0.f, 0.f};
    f32x4 acc[4] = {z4, z4, z4, z4};
    int row_ = t >> 4, g_ = t & 15;
    int hl_ = g_ >> 3, w8_ = (g_ & 7) * 8;   // granule -> (h_local, w-range)
    short8 pX[4], pB[4];
    float pY[4];
    #pragma unroll
    for (int j = 0; j < 4; j++) {            // chunk 0 prefetch; pX chunk-invariant
        int row = row_ + 16 * j;
        int h = zz * 16 + hl_;
        pX[j] = *(const short8*)&gxo[((size_t)b * LL + l0 + row) * 64 + w8_];
        pY[j] = bf2f(gyoT[((size_t)b * 64 + h) * LL + l0 + row]);
        pB[j] = *(const short8*)&fnchw[(((size_t)b * 64 + row) * 64 + h) * 64 + w8_];
    }
    for (int c = 0; c < 8; c++) {
        __syncthreads();
        #pragma unroll
        for (int j = 0; j < 4; j++) {
            int row = row_ + 16 * j;
            short8 a;
            #pragma unroll
            for (int e = 0; e < 8; e++)
                a[e] = (short)f2bf(bf2f(pX[j][e]) * pY[j]);
            *(short8*)&At[swz(row, g_ * 8, 128)] = a;
            *(short8*)&Bt[swz(row, g_ * 8, 128)] = pB[j];
        }
        __syncthreads();
        if (c < 7) {
            int h = zz * 16 + (c + 1) * 2 + hl_;
            #pragma unroll
            for (int j = 0; j < 4; j++) {
                int row = row_ + 16 * j;
                pY[j] = bf2f(gyoT[((size_t)b * 64 + h) * LL + l0 + row]);
                pB[j] = *(const short8*)&fnchw[(((size_t)b * 64 + row) * 64 + h) * 64 + w8_];
            }
        }
        int mrow = wid * 16 + (lane & 15);
        #pragma unroll
        for (int ks = 0; ks < 4; ks++) {
            int k0 = ks * 32 + (lane >> 4) * 8;
            short8 a = *(short8*)&At[swz(mrow, k0, 128)];
            #pragma unroll
            for (int n = 0; n < 4; n++) {
                short8 bb = *(short8*)&Bt[swz(n * 16 + (lane & 15), k0, 128)];
                MFMA16(acc[n], a, bb);
            }
        }
    }
    #pragma unroll
    for (int n = 0; n < 4; n++)
        #pragma unroll
        for (int r = 0; r < 4; r++) {
            int lr = wid * 16 + ((lane >> 4) << 2) + r;
            int cc = n * 16 + (lane & 15);
            sampz[(((size_t)zz * BB + b) * LL + l0 + lr) * 64 + cc] = acc[n][r];
        }
}

// ---------------- K6: out[bl][e] = sum_d (sum_z samp[z])[bl][d] * wff[e][d] -------
__global__ __launch_bounds__(256) void k_out(const float* __restrict__ samp,
        const float* __restrict__ wff, float* __restrict__ out) {
    __shared__ __align__(16) short At[4096], Bt[4096];
    const size_t SP = 1048576;
    int t = threadIdx.x, lane = t & 63, wid = t >> 6;
    int b = blockIdx.x, mtl = blockIdx.y, ez = blockIdx.z;  // b fastest
    int mt = b * 32 + mtl, e0 = ez * 64;
    #pragma unroll
    for (int j = 0; j < 4; j++) {
        int idx = t + 256 * j;
        int row = idx >> 4, kq = (idx & 15) << 2;
        size_t off = ((size_t)mt * 64 + row) * 64 + kq;
        float4 v0 = *(const float4*)&samp[off];
        float4 v1 = *(const float4*)&samp[off + SP];
        float4 v2 = *(const float4*)&samp[off + 2 * SP];
        float4 v3 = *(const float4*)&samp[off + 3 * SP];
        float4 vs = {v0.x + v1.x + v2.x + v3.x, v0.y + v1.y + v2.y + v3.y,
                     v0.z + v1.z + v2.z + v3.z, v0.w + v1.w + v2.w + v3.w};
        *(short4v*)&At[swz(row, kq, 64)] = cvt4(vs);
        float4 wv = *(const float4*)&wff[(size_t)(e0 + row) * 64 + kq];
        *(short4v*)&Bt[swz(row, kq, 64)] = cvt4(wv);
    }
    __syncthreads();
    f32x4 z = {0.f, 0.f, 0.f, 0.f};
    f32x4 acc[4] = {z, z, z, z};
    int mrow = wid * 16 + (lane & 15);
    #pragma unroll
    for (int ks = 0; ks < 2; ks++) {
        int k0 = ks * 32 + (lane >> 4) * 8;
        short8 a = *(short8*)&At[swz(mrow, k0, 64)];
        #pragma unroll
        for (int n = 0; n < 4; n++) {
            short8 bb = *(short8*)&Bt[swz(n * 16 + (lane & 15), k0, 64)];
            MFMA16(acc[n], a, bb);
        }
    }
    #pragma unroll
    for (int n = 0; n < 4; n++)
        #pragma unroll
        for (int r = 0; r < 4; r++) {
            int lr = wid * 16 + ((lane >> 4) << 2) + r;
            int ec = e0 + n * 16 + (lane & 15);
            out[((size_t)mt * 64 + lr) * EE + ec] = acc[n][r];
        }
}

extern "C" void kernel_launch(void* const* d_in, const int* in_sizes, int n_in,
                              void* d_out, int out_size, void* d_ws, size_t ws_size,
                              hipStream_t stream) {
    const float* tokens = (const float*)d_in[0];
    const float* pos    = (const float*)d_in[1];
    const float* wtf    = (const float*)d_in[2];
    const float* wff    = (const float*)d_in[3];
    const float* w1     = (const float*)d_in[4];
    const float* b1     = (const float*)d_in[5];
    const float* w2     = (const float*)d_in[6];
    const float* b2     = (const float*)d_in[7];
    const float* lsig   = (const float*)d_in[8];
    float* out = (float*)d_out;

    const size_t M1 = 1048576;
    float* ws    = (float*)d_ws;
    short* sbase = (short*)d_ws;
    short* gyiT  = sbase;               // [0,1M) shorts
    short* gxiT  = sbase + 1 * M1;      // [1M,2M)
    short* gyoT  = sbase + 2 * M1;      // [2M,3M)
    short* gxo   = sbase + 3 * M1;      // [3M,4M)
    short* projT = sbase + 4 * M1;      // [4M,5M) shorts = floats [2M,2.5M)
    float* fz    = ws + 3 * M1;         // 2 x 2M floats [3M,7M) (scatter partials)
    float* fA    = ws + 7 * M1;         // 2M floats NHWC
    float* fB    = ws + 9 * M1;         // 2M floats NHWC
    short* fnchw = (short*)(ws + 11 * M1);  // 2M shorts (bf16 NCHW) [11M,12M)
    float* samp  = ws + 12 * M1;        // 4 x 1M floats [12M,16M) (gather partials)
    short* w1b   = (short*)(ws + 16 * M1);  // 73728 bf16
    short* w2b   = w1b + 73728;             // 8192 bf16

    hipLaunchKernelGGL(k_gauss_proj, dim3(544), dim3(256), 0, stream,
                       pos, lsig, gyiT, gxiT, gyoT, gxo, w1, w2, w1b, w2b,
                       tokens, wtf, projT);
    hipLaunchKernelGGL(k_scatter, dim3(8, 32, 2), dim3(256), 0, stream,
                       projT, gyiT, gxiT, fz);
    hipLaunchKernelGGL(k_conv, dim3(8, 64), dim3(256), 0, stream,
                       fz, 2, fB, w1b, b1, w2b, b2, fnchw, 0);
    hipLaunchKernelGGL(k_conv, dim3(8, 64), dim3(256), 0, stream,
                       fB, 1, fA, w1b, b1, w2b, b2, fnchw, 0);
    hipLaunchKernelGGL(k_conv, dim3(8, 64), dim3(256), 0, stream,
                       fA, 1, fB, w1b, b1, w2b, b2, fnchw, 0);
    hipLaunchKernelGGL(k_conv, dim3(8, 64), dim3(256), 0, stream,
                       fB, 1, fA, w1b, b1, w2b, b2, fnchw, 0);
    hipLaunchKernelGGL(k_conv, dim3(8, 64), dim3(256), 0, stream,
                       fA, 1, fB, w1b, b1, w2b, b2, fnchw, 1);
    hipLaunchKernelGGL(k_gather, dim3(8, 32, 4), dim3(256), 0, stream,
                       fnchw, gyoT, gxo, samp);
    hipLaunchKernelGGL(k_out, dim3(8, 32, 8), dim3(256), 0, stream,
                       samp, wff, out);
}